// Round 3
// baseline (116.792 us; speedup 1.0000x reference)
//
#include <hip/hip_runtime.h>

// ---------------------------------------------------------------------------
// MultiHeadAttentionWindow: B=8 K=4000 D=256 H=8 DQ=DV=32 WIN=200 PAD=50 STEP=100
// Batch-chunked pipeline (chunk size bc picked from ws_size):
//   prep_weights : Wt[n][k] = bf16(W[k][n]) for Wq,Wk,Wv,Wo   (once)
//   per chunk [b0, b0+bc):
//     gemm256<0> : qb[b',t,h*32+dq]           (bf16, [bc*4000][256])
//     gemm256<1> : kb[b'][p=t+50][256]        (bf16, padded coords, [bc*4064][256])
//     gemm256<2> : vt[b'][h][dv][p=t+50]      (bf16, transposed, [bc*8][32][4064])
//     fill_edges : kb/vt p<50 := row p=50 (replicate), p in [4050,4064) := 0
//     attn_win   : per (b',h,window): causal cauchy softmax, rows 50..149
//     gemm256<3> : out[b0..] = ao @ Wo + bo (fp32)
// Round-2 fix: PV MFMA consumes K=32 per call -> k-loop must step by 32 (5
// chunks over j in [0,160)), and P must be fully initialized (all 10 tiles
// written; beyond-causal tiles are zero). Previously PV stepped by 16 ->
// double-counted j AND read uninitialized LDS into MFMA -> NaN.
// ---------------------------------------------------------------------------

typedef __bf16 bf16_t;
typedef __bf16 bf16x8 __attribute__((ext_vector_type(8)));
typedef float  f32x4  __attribute__((ext_vector_type(4)));

#define MFMA16(a, b, c) __builtin_amdgcn_mfma_f32_16x16x32_bf16((a), (b), (c), 0, 0, 0)

static __device__ __forceinline__ bf16x8 cvt8(float4 a, float4 b) {
  bf16x8 r;
  r[0] = (bf16_t)a.x; r[1] = (bf16_t)a.y; r[2] = (bf16_t)a.z; r[3] = (bf16_t)a.w;
  r[4] = (bf16_t)b.x; r[5] = (bf16_t)b.y; r[6] = (bf16_t)b.z; r[7] = (bf16_t)b.w;
  return r;
}

static __device__ __forceinline__ unsigned short bbits(bf16_t v) {
  union { bf16_t b; unsigned short u; } c; c.b = v; return c.u;
}

// ---- weight transpose + bf16 convert: Wt[n][k] = bf16(W[k][n]), 4 matrices ----
__global__ __launch_bounds__(256)
void prep_weights(const float* __restrict__ Wq, const float* __restrict__ Wk,
                  const float* __restrict__ Wv, const float* __restrict__ Wo,
                  bf16_t* __restrict__ wt) {
  const int mat  = blockIdx.x >> 6;
  const int tile = blockIdx.x & 63;
  const int kt = (tile >> 3) * 32, nt = (tile & 7) * 32;
  const float* W = (mat == 0) ? Wq : (mat == 1) ? Wk : (mat == 2) ? Wv : Wo;
  __shared__ float t[32][33];
  const int tx = threadIdx.x & 31, ty = threadIdx.x >> 5;  // ty 0..7
#pragma unroll
  for (int i = 0; i < 32; i += 8)
    t[ty + i][tx] = W[(size_t)(kt + ty + i) * 256 + nt + tx];
  __syncthreads();
  bf16_t* dst = wt + (size_t)mat * 65536;
#pragma unroll
  for (int i = 0; i < 32; i += 8)
    dst[(size_t)(nt + ty + i) * 256 + kt + tx] = (bf16_t)t[tx][ty + i];
}

// ---- GEMM: [M x 256] x [256 x 256] + bias, 128x128 tile, 4 waves ----
// MODE 0: fp32 in -> bf16 out row-major (qb)
// MODE 1: fp32 in -> bf16 out at row b'*4064 + t + 50 (kb)
// MODE 2: fp32 in -> bf16 out transposed vt[((b'*8+h)*32+dv)*4064 + t+50]
// MODE 3: bf16 in (ao) -> fp32 out row-major (d_out chunk)
template <int MODE>
__global__ __launch_bounds__(256)
void gemm256(const void* __restrict__ Xv, const bf16_t* __restrict__ Wt,
             const float* __restrict__ bias, void* __restrict__ Out, int M) {
  constexpr bool INB = (MODE == 3);
  const int m0 = blockIdx.x * 128;
  const int n0 = blockIdx.y * 128;
  __shared__ bf16_t la[128 * 40];  // stride 40 bf16 = 80 B rows (16B-aligned)
  __shared__ bf16_t lb[128 * 40];
  const int tid  = threadIdx.x;
  const int lane = tid & 63;
  const int wr   = ((tid >> 7) & 1) * 64;  // wave row offset
  const int wc   = ((tid >> 6) & 1) * 64;  // wave col offset
  const int lo   = lane & 15, hi = lane >> 4;
  const int arow = tid >> 1;           // 0..127
  const int acol = (tid & 1) * 16;     // 0 or 16
  int ar = m0 + arow; if (ar >= M) ar = M - 1;   // clamped staging row

  f32x4 acc[4][4] = {};

  for (int kk = 0; kk < 256; kk += 32) {
    if constexpr (!INB) {
      const float* X = (const float*)Xv + (size_t)ar * 256 + kk + acol;
      float4 x0 = ((const float4*)X)[0];
      float4 x1 = ((const float4*)X)[1];
      float4 x2 = ((const float4*)X)[2];
      float4 x3 = ((const float4*)X)[3];
      *(bf16x8*)&la[arow * 40 + acol]     = cvt8(x0, x1);
      *(bf16x8*)&la[arow * 40 + acol + 8] = cvt8(x2, x3);
    } else {
      const bf16_t* X = (const bf16_t*)Xv + (size_t)ar * 256 + kk + acol;
      *(bf16x8*)&la[arow * 40 + acol]     = ((const bf16x8*)X)[0];
      *(bf16x8*)&la[arow * 40 + acol + 8] = ((const bf16x8*)X)[1];
    }
    {
      const bf16_t* Wp = Wt + (size_t)(n0 + arow) * 256 + kk + acol;
      *(bf16x8*)&lb[arow * 40 + acol]     = ((const bf16x8*)Wp)[0];
      *(bf16x8*)&lb[arow * 40 + acol + 8] = ((const bf16x8*)Wp)[1];
    }
    __syncthreads();

    bf16x8 af[4], bfv[4];
#pragma unroll
    for (int mi = 0; mi < 4; ++mi)
      af[mi] = *(const bf16x8*)&la[(wr + mi * 16 + lo) * 40 + hi * 8];
#pragma unroll
    for (int ni = 0; ni < 4; ++ni)
      bfv[ni] = *(const bf16x8*)&lb[(wc + ni * 16 + lo) * 40 + hi * 8];
#pragma unroll
    for (int mi = 0; mi < 4; ++mi)
#pragma unroll
      for (int ni = 0; ni < 4; ++ni)
        acc[mi][ni] = MFMA16(af[mi], bfv[ni], acc[mi][ni]);
    __syncthreads();
  }

  // epilogue: C/D layout col = lane&15, row = (lane>>4)*4 + r  [m89-verified]
#pragma unroll
  for (int mi = 0; mi < 4; ++mi)
#pragma unroll
    for (int ni = 0; ni < 4; ++ni) {
      const int n   = n0 + wc + ni * 16 + lo;
      const float bia = bias[n];
      const int mb  = m0 + wr + mi * 16 + hi * 4;  // 4-aligned
      if (mb >= M) continue;                       // M % 4 == 0
      if constexpr (MODE == 0) {
        bf16_t* O = (bf16_t*)Out;
#pragma unroll
        for (int r = 0; r < 4; ++r)
          O[(size_t)(mb + r) * 256 + n] = (bf16_t)(acc[mi][ni][r] + bia);
      } else if constexpr (MODE == 1) {
        const int b = mb / 4000, t = mb - b * 4000;
        bf16_t* O = (bf16_t*)Out;
#pragma unroll
        for (int r = 0; r < 4; ++r)
          O[((size_t)b * 4064 + t + 50 + r) * 256 + n] = (bf16_t)(acc[mi][ni][r] + bia);
      } else if constexpr (MODE == 2) {
        const int b = mb / 4000, t = mb - b * 4000;
        const int h = n >> 5, dv = n & 31;
        bf16_t* O = (bf16_t*)Out + ((size_t)((b * 8 + h) * 32 + dv)) * 4064 + t + 50;
        unsigned short e0 = bbits((bf16_t)(acc[mi][ni][0] + bia));
        unsigned short e1 = bbits((bf16_t)(acc[mi][ni][1] + bia));
        unsigned short e2 = bbits((bf16_t)(acc[mi][ni][2] + bia));
        unsigned short e3 = bbits((bf16_t)(acc[mi][ni][3] + bia));
        unsigned* O32 = (unsigned*)O;  // (t+50) even -> 4B aligned
        O32[0] = (unsigned)e0 | ((unsigned)e1 << 16);
        O32[1] = (unsigned)e2 | ((unsigned)e3 << 16);
      } else {
        float* O = (float*)Out;
#pragma unroll
        for (int r = 0; r < 4; ++r)
          O[(size_t)(mb + r) * 256 + n] = acc[mi][ni][r] + bia;
      }
    }
}

// ---- fill replicate-pad edges + zero tails for kb and vt (nb batches) ----
__global__ void fill_edges(bf16_t* __restrict__ kb, bf16_t* __restrict__ vt, int nb) {
  const int idx = blockIdx.x * 256 + threadIdx.x;
  const int kcnt = nb * 64 * 256;
  if (idx < kcnt) {                    // kb: [nb][4064][256]
    const int b  = idx >> 14;
    const int pp = (idx >> 8) & 63;    // 0..63
    const int nn = idx & 255;
    const int p  = (pp < 50) ? pp : pp + 4000;   // [0,50) and [4050,4064)
    bf16_t v = (pp < 50) ? kb[((size_t)b * 4064 + 50) * 256 + nn] : (bf16_t)0.f;
    kb[((size_t)b * 4064 + p) * 256 + nn] = v;
  } else {                             // vt: [nb*8][32][4064]
    const int j  = idx - kcnt;
    const int bh = j >> 11;
    const int dv = (j >> 6) & 31;
    const int pp = j & 63;
    const int p  = (pp < 50) ? pp : pp + 4000;
    bf16_t v = (pp < 50) ? vt[((size_t)bh * 32 + dv) * 4064 + 50] : (bf16_t)0.f;
    vt[((size_t)bh * 32 + dv) * 4064 + p] = v;
  }
}

// ---- windowed attention: one block per (b',h,window), 7 waves = 7 row-strips ----
__global__ __launch_bounds__(448)
void attn_win(const bf16_t* __restrict__ qb, const bf16_t* __restrict__ kb,
              const bf16_t* __restrict__ vt, bf16_t* __restrict__ ao) {
  const int blk = blockIdx.x;
  const int n = blk % 40;
  const int h = (blk / 40) & 7;
  const int b = blk / 320;
  const int wv = threadIdx.x >> 6;     // strip 0..6, rows i in [50+16wv, 66+16wv)
  const int lane = threadIdx.x & 63;
  const int lo = lane & 15, hi = lane >> 4;

  __shared__ __align__(16) bf16_t P[7][16][168];  // per-wave P bounce (attn weights)

  const int i0 = 50 + 16 * wv;
  int jtmax = (65 + 16 * wv) >> 4;     // covers causal j <= i_max of this strip
  if (jtmax > 9) jtmax = 9;

  // Q fragment: A[m=lo][k=hi*8+jj]; row lo -> token t = n*100 + 16wv + lo
  int tq = n * 100 + 16 * wv + lo;
  if (tq > 3999) tq = 3999;            // rows i>=150 are discarded at store
  const bf16x8 qf = *(const bf16x8*)&qb[((size_t)b * 4000 + tq) * 256 + h * 32 + hi * 8];

  const f32x4 zero = {0.f, 0.f, 0.f, 0.f};
  f32x4 sc[10];

  // scores: S = Q . K^T  (B-frag: fixed j = lo, 8 consecutive k; K=32 = head dim)
#pragma unroll
  for (int jt = 0; jt < 10; ++jt) {
    if (jt <= jtmax) {
      const bf16x8 kf = *(const bf16x8*)&kb[((size_t)(b * 4064 + n * 100 + jt * 16 + lo)) * 256 + h * 32 + hi * 8];
      sc[jt] = MFMA16(qf, kf, zero);
    } else sc[jt] = zero;
  }

  // mask + cauchy + scale; row max (max >= 0 since diagonal contributes 0)
  const float scale = 0.07071067811865475f;  // 1/sqrt(200)
  const float NEG = -1e30f;                  // finite mask (fast-math safe)
  float m4[4] = {0.f, 0.f, 0.f, 0.f};
#pragma unroll
  for (int jt = 0; jt < 10; ++jt) if (jt <= jtmax) {
#pragma unroll
    for (int r = 0; r < 4; ++r) {
      const int i = i0 + hi * 4 + r;
      const int j = jt * 16 + lo;
      const int d = i - j;
      float v;
      if (d < 0)        v = NEG;
      else if (d == 0)  v = 0.f;
      else {
        const float df = (float)d;
        v = sc[jt][r] * scale * __builtin_amdgcn_rcpf(1.f + 0.25f * df * df);
      }
      sc[jt][r] = v;
      m4[r] = fmaxf(m4[r], v);
    }
  }
#pragma unroll
  for (int msk = 1; msk < 16; msk <<= 1)
#pragma unroll
    for (int r = 0; r < 4; ++r)
      m4[r] = fmaxf(m4[r], __shfl_xor(m4[r], msk, 64));

  // exp + row sum (masked entries: exp(NEG-m)==0; jt>jtmax entries stay 0)
  float s4[4] = {0.f, 0.f, 0.f, 0.f};
#pragma unroll
  for (int jt = 0; jt < 10; ++jt) if (jt <= jtmax) {
#pragma unroll
    for (int r = 0; r < 4; ++r) {
      const float e = __expf(sc[jt][r] - m4[r]);
      sc[jt][r] = e;
      s4[r] += e;
    }
  }
#pragma unroll
  for (int msk = 1; msk < 16; msk <<= 1)
#pragma unroll
    for (int r = 0; r < 4; ++r)
      s4[r] += __shfl_xor(s4[r], msk, 64);

  float ri4[4];
#pragma unroll
  for (int r = 0; r < 4; ++r) ri4[r] = 1.f / s4[r];

  // write P (D-layout) to LDS — ALL 10 tiles, so PV never reads uninit LDS.
  // Tiles jt > jtmax carry sc==0 -> P==0 (they're fully causal-masked).
#pragma unroll
  for (int jt = 0; jt < 10; ++jt)
#pragma unroll
    for (int r = 0; r < 4; ++r)
      P[wv][hi * 4 + r][jt * 16 + lo] = (bf16_t)(sc[jt][r] * ri4[r]);

  // PV: O = P . V ; K=32 per MFMA -> 5 chunks over j in [0,160)
  f32x4 o0 = zero, o1 = zero;
  const size_t vbase = ((size_t)((b * 8 + h) * 32)) * 4064 + n * 100;
  const int reach = jtmax * 16 + 16;   // P columns < reach may be nonzero
#pragma unroll
  for (int kt = 0; kt < 5; ++kt) if (kt * 32 < reach) {
    const bf16x8 pf = *(const bf16x8*)&P[wv][lo][kt * 32 + hi * 8];
    const bf16x8 v0 = *(const bf16x8*)&vt[vbase + (size_t)lo * 4064 + kt * 32 + hi * 8];
    const bf16x8 v1 = *(const bf16x8*)&vt[vbase + (size_t)(16 + lo) * 4064 + kt * 32 + hi * 8];
    o0 = MFMA16(pf, v0, o0);
    o1 = MFMA16(pf, v1, o1);
  }

  // store central rows only (i in [50,150))
#pragma unroll
  for (int r = 0; r < 4; ++r) {
    const int i = i0 + hi * 4 + r;
    if (i < 150) {
      const int t = n * 100 + i - 50;
      bf16_t* op = &ao[((size_t)b * 4000 + t) * 256 + h * 32];
      op[lo]      = (bf16_t)o0[r];
      op[16 + lo] = (bf16_t)o1[r];
    }
  }
}

// ---------------------------------------------------------------------------
extern "C" void kernel_launch(void* const* d_in, const int* in_sizes, int n_in,
                              void* d_out, int out_size, void* d_ws, size_t ws_size,
                              hipStream_t stream) {
  (void)in_sizes; (void)n_in; (void)out_size;
  const float* query = (const float*)d_in[0];
  const float* key   = (const float*)d_in[1];
  const float* value = (const float*)d_in[2];
  const float* Wq = (const float*)d_in[3];
  const float* bq = (const float*)d_in[4];
  const float* Wk = (const float*)d_in[5];
  const float* bk = (const float*)d_in[6];
  const float* Wv = (const float*)d_in[7];
  const float* bv = (const float*)d_in[8];
  const float* Wo = (const float*)d_in[9];
  const float* bo = (const float*)d_in[10];

  // pick largest batch chunk bc that fits ws_size:
  // bytes(bc) = 524288 (wt) + bc * 8,257,536 (qb+kb+vt+ao per batch)
  int bc = 8;
  while (bc > 1 && 524288ull + (unsigned long long)bc * 8257536ull > (unsigned long long)ws_size)
    bc >>= 1;

  bf16_t* wt = (bf16_t*)d_ws;                           // 4 * 65536
  bf16_t* qb = wt + 4 * 65536;                          // bc*4000*256
  bf16_t* kb = qb + (size_t)bc * 4000 * 256;            // bc*4064*256
  bf16_t* vt = kb + (size_t)bc * 4064 * 256;            // bc*8*32*4064
  bf16_t* ao = vt + (size_t)bc * 8 * 32 * 4064;         // bc*4000*256

  prep_weights<<<256, 256, 0, stream>>>(Wq, Wk, Wv, Wo, wt);

  for (int b0 = 0; b0 < 8; b0 += bc) {
    const int M = bc * 4000;
    const int mblk = (M + 127) / 128;
    const float* qx = query + (size_t)b0 * 4000 * 256;
    const float* kx = key   + (size_t)b0 * 4000 * 256;
    const float* vx = value + (size_t)b0 * 4000 * 256;
    float* ox = (float*)d_out + (size_t)b0 * 4000 * 256;

    gemm256<0><<<dim3(mblk, 2), 256, 0, stream>>>(qx, wt + 0 * 65536, bq, qb, M);
    gemm256<1><<<dim3(mblk, 2), 256, 0, stream>>>(kx, wt + 1 * 65536, bk, kb, M);
    gemm256<2><<<dim3(mblk, 2), 256, 0, stream>>>(vx, wt + 2 * 65536, bv, vt, M);
    fill_edges<<<bc * 128, 256, 0, stream>>>(kb, vt, bc);
    attn_win<<<bc * 320, 448, 0, stream>>>(qb, kb, vt, ao);
    gemm256<3><<<dim3(mblk, 2), 256, 0, stream>>>(ao, wt + 3 * 65536, bo, ox, M);
  }
}

// Round 4
// 112.541 us; speedup vs baseline: 1.0378x; 1.0378x over previous
//
#include <hip/hip_runtime.h>

// ---------------------------------------------------------------------------
// MultiHeadAttentionWindow: B=8 K=4000 D=256 H=8 DQ=DV=32 WIN=200 PAD=50 STEP=100
// Batch-chunked pipeline (chunk size bc picked from ws_size):
//   prep_weights : Wt[n][k] = bf16(W[k][n]) for Wq,Wk,Wv,Wo   (once)
//   per chunk [b0, b0+bc):
//     gemm256<0> : qb[b',t,h*32+dq] * 1/sqrt(200)  (bf16, [bc*4000][256])
//     gemm256<1> : kb[b'][p=t+50][256]        (bf16, padded coords, [bc*4064][256])
//     gemm256<2> : vt[b'][h][dv][p=t+50]      (bf16, transposed, [bc*8][32][4064])
//     fill_edges : kb/vt p<50 := row p=50 (replicate), p in [4050,4064) := 0
//     attn_win   : per (b',h,window): causal cauchy softmax, rows 50..149
//     gemm256<3> : out[b0..] = ao @ Wo + bo (fp32)
// Round-3: attn softmax restructured to have ZERO cross-lane ops:
//   - no max-subtraction (scores bounded ~|0.3|, exp safe)
//   - denominator = E @ ones via a 3rd MFMA chain (same C/D layout as PV out)
//   - normalize AFTER PV: out = (E@V) * rcp(E@1)
// ---------------------------------------------------------------------------

typedef __bf16 bf16_t;
typedef __bf16 bf16x8 __attribute__((ext_vector_type(8)));
typedef float  f32x4  __attribute__((ext_vector_type(4)));

#define MFMA16(a, b, c) __builtin_amdgcn_mfma_f32_16x16x32_bf16((a), (b), (c), 0, 0, 0)

static __device__ __forceinline__ bf16x8 cvt8(float4 a, float4 b) {
  bf16x8 r;
  r[0] = (bf16_t)a.x; r[1] = (bf16_t)a.y; r[2] = (bf16_t)a.z; r[3] = (bf16_t)a.w;
  r[4] = (bf16_t)b.x; r[5] = (bf16_t)b.y; r[6] = (bf16_t)b.z; r[7] = (bf16_t)b.w;
  return r;
}

static __device__ __forceinline__ unsigned short bbits(bf16_t v) {
  union { bf16_t b; unsigned short u; } c; c.b = v; return c.u;
}

// ---- weight transpose + bf16 convert: Wt[n][k] = bf16(W[k][n]), 4 matrices ----
__global__ __launch_bounds__(256)
void prep_weights(const float* __restrict__ Wq, const float* __restrict__ Wk,
                  const float* __restrict__ Wv, const float* __restrict__ Wo,
                  bf16_t* __restrict__ wt) {
  const int mat  = blockIdx.x >> 6;
  const int tile = blockIdx.x & 63;
  const int kt = (tile >> 3) * 32, nt = (tile & 7) * 32;
  const float* W = (mat == 0) ? Wq : (mat == 1) ? Wk : (mat == 2) ? Wv : Wo;
  __shared__ float t[32][33];
  const int tx = threadIdx.x & 31, ty = threadIdx.x >> 5;  // ty 0..7
#pragma unroll
  for (int i = 0; i < 32; i += 8)
    t[ty + i][tx] = W[(size_t)(kt + ty + i) * 256 + nt + tx];
  __syncthreads();
  bf16_t* dst = wt + (size_t)mat * 65536;
#pragma unroll
  for (int i = 0; i < 32; i += 8)
    dst[(size_t)(nt + ty + i) * 256 + kt + tx] = (bf16_t)t[tx][ty + i];
}

// ---- GEMM: [M x 256] x [256 x 256] + bias, 128x128 tile, 4 waves ----
// MODE 0: fp32 in -> bf16 out row-major (qb), scaled by oscale
// MODE 1: fp32 in -> bf16 out at row b'*4064 + t + 50 (kb)
// MODE 2: fp32 in -> bf16 out transposed vt[((b'*8+h)*32+dv)*4064 + t+50]
// MODE 3: bf16 in (ao) -> fp32 out row-major (d_out chunk)
template <int MODE>
__global__ __launch_bounds__(256)
void gemm256(const void* __restrict__ Xv, const bf16_t* __restrict__ Wt,
             const float* __restrict__ bias, void* __restrict__ Out, int M,
             float oscale) {
  constexpr bool INB = (MODE == 3);
  const int m0 = blockIdx.x * 128;
  const int n0 = blockIdx.y * 128;
  __shared__ bf16_t la[128 * 40];  // stride 40 bf16 = 80 B rows (16B-aligned)
  __shared__ bf16_t lb[128 * 40];
  const int tid  = threadIdx.x;
  const int lane = tid & 63;
  const int wr   = ((tid >> 7) & 1) * 64;  // wave row offset
  const int wc   = ((tid >> 6) & 1) * 64;  // wave col offset
  const int lo   = lane & 15, hi = lane >> 4;
  const int arow = tid >> 1;           // 0..127
  const int acol = (tid & 1) * 16;     // 0 or 16
  int ar = m0 + arow; if (ar >= M) ar = M - 1;   // clamped staging row

  f32x4 acc[4][4] = {};

  for (int kk = 0; kk < 256; kk += 32) {
    if constexpr (!INB) {
      const float* X = (const float*)Xv + (size_t)ar * 256 + kk + acol;
      float4 x0 = ((const float4*)X)[0];
      float4 x1 = ((const float4*)X)[1];
      float4 x2 = ((const float4*)X)[2];
      float4 x3 = ((const float4*)X)[3];
      *(bf16x8*)&la[arow * 40 + acol]     = cvt8(x0, x1);
      *(bf16x8*)&la[arow * 40 + acol + 8] = cvt8(x2, x3);
    } else {
      const bf16_t* X = (const bf16_t*)Xv + (size_t)ar * 256 + kk + acol;
      *(bf16x8*)&la[arow * 40 + acol]     = ((const bf16x8*)X)[0];
      *(bf16x8*)&la[arow * 40 + acol + 8] = ((const bf16x8*)X)[1];
    }
    {
      const bf16_t* Wp = Wt + (size_t)(n0 + arow) * 256 + kk + acol;
      *(bf16x8*)&lb[arow * 40 + acol]     = ((const bf16x8*)Wp)[0];
      *(bf16x8*)&lb[arow * 40 + acol + 8] = ((const bf16x8*)Wp)[1];
    }
    __syncthreads();

    bf16x8 af[4], bfv[4];
#pragma unroll
    for (int mi = 0; mi < 4; ++mi)
      af[mi] = *(const bf16x8*)&la[(wr + mi * 16 + lo) * 40 + hi * 8];
#pragma unroll
    for (int ni = 0; ni < 4; ++ni)
      bfv[ni] = *(const bf16x8*)&lb[(wc + ni * 16 + lo) * 40 + hi * 8];
#pragma unroll
    for (int mi = 0; mi < 4; ++mi)
#pragma unroll
      for (int ni = 0; ni < 4; ++ni)
        acc[mi][ni] = MFMA16(af[mi], bfv[ni], acc[mi][ni]);
    __syncthreads();
  }

  // epilogue: C/D layout col = lane&15, row = (lane>>4)*4 + r  [m89-verified]
#pragma unroll
  for (int mi = 0; mi < 4; ++mi)
#pragma unroll
    for (int ni = 0; ni < 4; ++ni) {
      const int n   = n0 + wc + ni * 16 + lo;
      const float bia = bias[n];
      const int mb  = m0 + wr + mi * 16 + hi * 4;  // 4-aligned
      if (mb >= M) continue;                       // M % 4 == 0
      if constexpr (MODE == 0) {
        bf16_t* O = (bf16_t*)Out;
#pragma unroll
        for (int r = 0; r < 4; ++r)
          O[(size_t)(mb + r) * 256 + n] = (bf16_t)((acc[mi][ni][r] + bia) * oscale);
      } else if constexpr (MODE == 1) {
        const int b = mb / 4000, t = mb - b * 4000;
        bf16_t* O = (bf16_t*)Out;
#pragma unroll
        for (int r = 0; r < 4; ++r)
          O[((size_t)b * 4064 + t + 50 + r) * 256 + n] = (bf16_t)(acc[mi][ni][r] + bia);
      } else if constexpr (MODE == 2) {
        const int b = mb / 4000, t = mb - b * 4000;
        const int h = n >> 5, dv = n & 31;
        bf16_t* O = (bf16_t*)Out + ((size_t)((b * 8 + h) * 32 + dv)) * 4064 + t + 50;
        unsigned short e0 = bbits((bf16_t)(acc[mi][ni][0] + bia));
        unsigned short e1 = bbits((bf16_t)(acc[mi][ni][1] + bia));
        unsigned short e2 = bbits((bf16_t)(acc[mi][ni][2] + bia));
        unsigned short e3 = bbits((bf16_t)(acc[mi][ni][3] + bia));
        unsigned* O32 = (unsigned*)O;  // (t+50) even -> 4B aligned
        O32[0] = (unsigned)e0 | ((unsigned)e1 << 16);
        O32[1] = (unsigned)e2 | ((unsigned)e3 << 16);
      } else {
        float* O = (float*)Out;
#pragma unroll
        for (int r = 0; r < 4; ++r)
          O[(size_t)(mb + r) * 256 + n] = acc[mi][ni][r] + bia;
      }
    }
}

// ---- fill replicate-pad edges + zero tails for kb and vt (nb batches) ----
__global__ void fill_edges(bf16_t* __restrict__ kb, bf16_t* __restrict__ vt, int nb) {
  const int idx = blockIdx.x * 256 + threadIdx.x;
  const int kcnt = nb * 64 * 256;
  if (idx < kcnt) {                    // kb: [nb][4064][256]
    const int b  = idx >> 14;
    const int pp = (idx >> 8) & 63;    // 0..63
    const int nn = idx & 255;
    const int p  = (pp < 50) ? pp : pp + 4000;   // [0,50) and [4050,4064)
    bf16_t v = (pp < 50) ? kb[((size_t)b * 4064 + 50) * 256 + nn] : (bf16_t)0.f;
    kb[((size_t)b * 4064 + p) * 256 + nn] = v;
  } else {                             // vt: [nb*8][32][4064]
    const int j  = idx - kcnt;
    const int bh = j >> 11;
    const int dv = (j >> 6) & 31;
    const int pp = j & 63;
    const int p  = (pp < 50) ? pp : pp + 4000;
    bf16_t v = (pp < 50) ? vt[((size_t)bh * 32 + dv) * 4064 + 50] : (bf16_t)0.f;
    vt[((size_t)bh * 32 + dv) * 4064 + p] = v;
  }
}

// ---- windowed attention: one block per (b',h,window), 7 waves = 7 row-strips ----
// No cross-lane ops: unnormalized E -> LDS; denom via E@ones MFMA; post-scale.
__global__ __launch_bounds__(448)
void attn_win(const bf16_t* __restrict__ qb, const bf16_t* __restrict__ kb,
              const bf16_t* __restrict__ vt, bf16_t* __restrict__ ao) {
  const int blk = blockIdx.x;
  const int n = blk % 40;
  const int h = (blk / 40) & 7;
  const int b = blk / 320;
  const int wv = threadIdx.x >> 6;     // strip 0..6, rows i in [50+16wv, 66+16wv)
  const int lane = threadIdx.x & 63;
  const int lo = lane & 15, hi = lane >> 4;

  __shared__ __align__(16) bf16_t E[7][16][168];  // unnormalized exp-scores

  const int i0 = 50 + 16 * wv;
  int jtmax = (65 + 16 * wv) >> 4;     // last tile with any unmasked element
  if (jtmax > 9) jtmax = 9;

  // Q fragment (pre-scaled by 1/sqrt(200)): row lo -> token t = n*100+16wv+lo
  int tq = n * 100 + 16 * wv + lo;
  if (tq > 3999) tq = 3999;            // rows i>=150 are discarded at store
  const bf16x8 qf = *(const bf16x8*)&qb[((size_t)b * 4000 + tq) * 256 + h * 32 + hi * 8];

  const f32x4 zero = {0.f, 0.f, 0.f, 0.f};

  // scores S = Q.K^T (K=32 = head dim), then E = cauchy-weighted exp, to LDS.
  const int dbase = i0 + hi * 4 - lo;  // d = dbase + r - 16*jt
  for (int jt = 0; jt <= jtmax; ++jt) {
    const bf16x8 kf = *(const bf16x8*)&kb[((size_t)(b * 4064 + n * 100 + jt * 16 + lo)) * 256 + h * 32 + hi * 8];
    const f32x4 s = MFMA16(qf, kf, zero);
#pragma unroll
    for (int r = 0; r < 4; ++r) {
      const int d = dbase + r - jt * 16;
      const float df = (float)d;
      float c = __builtin_amdgcn_rcpf(__builtin_fmaf(0.25f * df, df, 1.f));
      c = (d == 0) ? 0.f : c;          // eye-mask: diagonal score -> 0 -> e=1
      float e = __expf(s[r] * c);
      e = (d < 0) ? 0.f : e;           // causal mask
      E[wv][hi * 4 + r][jt * 16 + lo] = (bf16_t)e;
    }
  }
  for (int jt = jtmax + 1; jt < 10; ++jt) {   // fully-masked tiles: zero-fill
#pragma unroll
    for (int r = 0; r < 4; ++r)
      E[wv][hi * 4 + r][jt * 16 + lo] = (bf16_t)0.f;
  }

  // ones B-fragment for the row-sum MFMA chain
  bf16x8 onesf;
#pragma unroll
  for (int u = 0; u < 8; ++u) onesf[u] = (bf16_t)1.0f;

  // PV + denom: o = E@V, s = E@1 ; K=32 per MFMA -> up to 5 chunks over j<160
  f32x4 o0 = zero, o1 = zero, sm = zero;
  const size_t vbase = ((size_t)((b * 8 + h) * 32)) * 4064 + n * 100;
  const int reach = jtmax * 16 + 16;   // E columns < reach may be nonzero
#pragma unroll
  for (int kt = 0; kt < 5; ++kt) if (kt * 32 < reach) {
    const bf16x8 pf = *(const bf16x8*)&E[wv][lo][kt * 32 + hi * 8];
    const bf16x8 v0 = *(const bf16x8*)&vt[vbase + (size_t)lo * 4064 + kt * 32 + hi * 8];
    const bf16x8 v1 = *(const bf16x8*)&vt[vbase + (size_t)(16 + lo) * 4064 + kt * 32 + hi * 8];
    o0 = MFMA16(pf, v0, o0);
    o1 = MFMA16(pf, v1, o1);
    sm = MFMA16(pf, onesf, sm);
  }

  // store central rows (i in [50,150)): out = o * rcp(rowsum); rowsum >= 1
#pragma unroll
  for (int r = 0; r < 4; ++r) {
    const int i = i0 + hi * 4 + r;
    if (i < 150) {
      const float ri = __builtin_amdgcn_rcpf(sm[r]);
      const int t = n * 100 + i - 50;
      bf16_t* op = &ao[((size_t)b * 4000 + t) * 256 + h * 32];
      op[lo]      = (bf16_t)(o0[r] * ri);
      op[16 + lo] = (bf16_t)(o1[r] * ri);
    }
  }
}

// ---------------------------------------------------------------------------
extern "C" void kernel_launch(void* const* d_in, const int* in_sizes, int n_in,
                              void* d_out, int out_size, void* d_ws, size_t ws_size,
                              hipStream_t stream) {
  (void)in_sizes; (void)n_in; (void)out_size;
  const float* query = (const float*)d_in[0];
  const float* key   = (const float*)d_in[1];
  const float* value = (const float*)d_in[2];
  const float* Wq = (const float*)d_in[3];
  const float* bq = (const float*)d_in[4];
  const float* Wk = (const float*)d_in[5];
  const float* bk = (const float*)d_in[6];
  const float* Wv = (const float*)d_in[7];
  const float* bv = (const float*)d_in[8];
  const float* Wo = (const float*)d_in[9];
  const float* bo = (const float*)d_in[10];

  // pick largest batch chunk bc that fits ws_size:
  // bytes(bc) = 524288 (wt) + bc * 8,257,536 (qb+kb+vt+ao per batch)
  int bc = 8;
  while (bc > 1 && 524288ull + (unsigned long long)bc * 8257536ull > (unsigned long long)ws_size)
    bc >>= 1;

  bf16_t* wt = (bf16_t*)d_ws;                           // 4 * 65536
  bf16_t* qb = wt + 4 * 65536;                          // bc*4000*256
  bf16_t* kb = qb + (size_t)bc * 4000 * 256;            // bc*4064*256
  bf16_t* vt = kb + (size_t)bc * 4064 * 256;            // bc*8*32*4064
  bf16_t* ao = vt + (size_t)bc * 8 * 32 * 4064;         // bc*4000*256

  prep_weights<<<256, 256, 0, stream>>>(Wq, Wk, Wv, Wo, wt);

  const float qscale = 0.07071067811865475f;  // 1/sqrt(200) folded into qb

  for (int b0 = 0; b0 < 8; b0 += bc) {
    const int M = bc * 4000;
    const int mblk = (M + 127) / 128;
    const float* qx = query + (size_t)b0 * 4000 * 256;
    const float* kx = key   + (size_t)b0 * 4000 * 256;
    const float* vx = value + (size_t)b0 * 4000 * 256;
    float* ox = (float*)d_out + (size_t)b0 * 4000 * 256;

    gemm256<0><<<dim3(mblk, 2), 256, 0, stream>>>(qx, wt + 0 * 65536, bq, qb, M, qscale);
    gemm256<1><<<dim3(mblk, 2), 256, 0, stream>>>(kx, wt + 1 * 65536, bk, kb, M, 1.f);
    gemm256<2><<<dim3(mblk, 2), 256, 0, stream>>>(vx, wt + 2 * 65536, bv, vt, M, 1.f);
    fill_edges<<<bc * 128, 256, 0, stream>>>(kb, vt, bc);
    attn_win<<<bc * 320, 448, 0, stream>>>(qb, kb, vt, ao);
    gemm256<3><<<dim3(mblk, 2), 256, 0, stream>>>(ao, wt + 3 * 65536, bo, ox, M, 1.f);
  }
}

// Round 6
// 106.177 us; speedup vs baseline: 1.1000x; 1.0599x over previous
//
#include <hip/hip_runtime.h>

// ---------------------------------------------------------------------------
// MultiHeadAttentionWindow: B=8 K=4000 D=256 H=8 DQ=DV=32 WIN=200 PAD=50 STEP=100
// Pipeline (batch chunk bc from ws_size):
//   prep_weights : Wt[n][k] = bf16(W[k][n]) for Wq,Wk,Wv,Wo   (once)
//   per chunk:
//     gemm256<0> : qb = (x@Wq+bq)/sqrt(200)   (bf16 [bc*4000][256])
//     gemm256<1> : kb (padded coords [bc*4064][256])
//     gemm256<2> : vt (transposed [bc*8][32][4064])
//     fill_edges : replicate-pad edges, zero tails
//     attn_win   : causal cauchy softmax windows, rows 50..149
//     gemm256<3> : out = ao @ Wo + bo (fp32)
// Round-5/6:
//   - gemm: 64m x 256n(full-N) tile, 8 waves -> A fetched ONCE (was 2x);
//     traffic/GEMM ~49MB (~8us floor).
//   - attn: E bounced through per-wave 16x32 LDS chunk (PV consumes 32 cols
//     per MFMA chunk anyway): LDS 37.9KB -> 9KB, block/CU cap 4 -> 17.
//   - (r6) fixed missing oscale arg on gemm256<3> call; default added.
// ---------------------------------------------------------------------------

typedef __bf16 bf16_t;
typedef __bf16 bf16x4 __attribute__((ext_vector_type(4)));
typedef __bf16 bf16x8 __attribute__((ext_vector_type(8)));
typedef float  f32x4  __attribute__((ext_vector_type(4)));

#define MFMA16(a, b, c) __builtin_amdgcn_mfma_f32_16x16x32_bf16((a), (b), (c), 0, 0, 0)

static __device__ __forceinline__ bf16x4 cvt4(float4 a) {
  bf16x4 r;
  r[0] = (bf16_t)a.x; r[1] = (bf16_t)a.y; r[2] = (bf16_t)a.z; r[3] = (bf16_t)a.w;
  return r;
}

static __device__ __forceinline__ unsigned short bbits(bf16_t v) {
  union { bf16_t b; unsigned short u; } c; c.b = v; return c.u;
}

// ---- weight transpose + bf16 convert: Wt[n][k] = bf16(W[k][n]), 4 matrices ----
__global__ __launch_bounds__(256)
void prep_weights(const float* __restrict__ Wq, const float* __restrict__ Wk,
                  const float* __restrict__ Wv, const float* __restrict__ Wo,
                  bf16_t* __restrict__ wt) {
  const int mat  = blockIdx.x >> 6;
  const int tile = blockIdx.x & 63;
  const int kt = (tile >> 3) * 32, nt = (tile & 7) * 32;
  const float* W = (mat == 0) ? Wq : (mat == 1) ? Wk : (mat == 2) ? Wv : Wo;
  __shared__ float t[32][33];
  const int tx = threadIdx.x & 31, ty = threadIdx.x >> 5;  // ty 0..7
#pragma unroll
  for (int i = 0; i < 32; i += 8)
    t[ty + i][tx] = W[(size_t)(kt + ty + i) * 256 + nt + tx];
  __syncthreads();
  bf16_t* dst = wt + (size_t)mat * 65536;
#pragma unroll
  for (int i = 0; i < 32; i += 8)
    dst[(size_t)(nt + ty + i) * 256 + kt + tx] = (bf16_t)t[tx][ty + i];
}

// ---- GEMM: [M x 256] x [256 x 256] + bias; 64m x 256n tile, 8 waves ----
// wave (wm = wv&3, wn = wv>>2): 16 x 128 out, acc = 8 x f32x4.
// MODE 0: fp32 in -> bf16 out row-major, scaled by oscale (qb)
// MODE 1: fp32 in -> bf16 out at row b'*4064 + t + 50 (kb)
// MODE 2: fp32 in -> bf16 out transposed vt[((b'*8+h)*32+dv)*4064 + t+50]
// MODE 3: bf16 in (ao) -> fp32 out row-major (d_out chunk)
template <int MODE>
__global__ __launch_bounds__(512)
void gemm256(const void* __restrict__ Xv, const bf16_t* __restrict__ Wt,
             const float* __restrict__ bias, void* __restrict__ Out, int M,
             float oscale = 1.f) {
  constexpr bool INB = (MODE == 3);
  const int m0 = blockIdx.x * 64;
  __shared__ bf16_t la[64 * 40];    // A tile 64x32, stride 40 (80B rows)
  __shared__ bf16_t lb[256 * 40];   // B tile 256x32, stride 40
  const int tid  = threadIdx.x;
  const int lane = tid & 63;
  const int wv   = tid >> 6;            // 0..7
  const int wm   = (wv & 3) * 16;       // wave row offset in tile
  const int wn   = (wv >> 2) * 128;     // wave col offset
  const int lo   = lane & 15, hi = lane >> 4;
  int ar = m0 + (tid >> 3); if (ar >= M) ar = M - 1;  // A staging row (clamped)

  f32x4 acc[8] = {};

  for (int kk = 0; kk < 256; kk += 32) {
    // stage A (64 x 32): 512 threads x 4 elems
    if constexpr (!INB) {
      const float* X = (const float*)Xv + (size_t)ar * 256 + kk + (tid & 7) * 4;
      *(bf16x4*)&la[(tid >> 3) * 40 + (tid & 7) * 4] = cvt4(*(const float4*)X);
    } else {
      const bf16_t* X = (const bf16_t*)Xv + (size_t)ar * 256 + kk + (tid & 7) * 4;
      *(bf16x4*)&la[(tid >> 3) * 40 + (tid & 7) * 4] = *(const bf16x4*)X;
    }
    // stage B (256 x 32): 512 threads x 16 elems (half row each)
    {
      const bf16_t* Wp = Wt + (size_t)(tid >> 1) * 256 + kk + (tid & 1) * 16;
      bf16_t* dst = &lb[(tid >> 1) * 40 + (tid & 1) * 16];
      *(bf16x8*)dst       = ((const bf16x8*)Wp)[0];
      *(bf16x8*)(dst + 8) = ((const bf16x8*)Wp)[1];
    }
    __syncthreads();

    const bf16x8 af = *(const bf16x8*)&la[(wm + lo) * 40 + hi * 8];
#pragma unroll
    for (int ni = 0; ni < 8; ++ni) {
      const bf16x8 bfv = *(const bf16x8*)&lb[(wn + ni * 16 + lo) * 40 + hi * 8];
      acc[ni] = MFMA16(af, bfv, acc[ni]);
    }
    __syncthreads();
  }

  // epilogue: C/D layout col = lane&15, row = (lane>>4)*4 + r  [m89-verified]
#pragma unroll
  for (int ni = 0; ni < 8; ++ni) {
    const int n   = wn + ni * 16 + lo;
    const float bia = bias[n];
    const int mb  = m0 + wm + hi * 4;   // 4-aligned
    if (mb >= M) continue;              // M % 4 == 0
    if constexpr (MODE == 0) {
      bf16_t* O = (bf16_t*)Out;
#pragma unroll
      for (int r = 0; r < 4; ++r)
        O[(size_t)(mb + r) * 256 + n] = (bf16_t)((acc[ni][r] + bia) * oscale);
    } else if constexpr (MODE == 1) {
      const int b = mb / 4000, t = mb - b * 4000;
      bf16_t* O = (bf16_t*)Out;
#pragma unroll
      for (int r = 0; r < 4; ++r)
        O[((size_t)b * 4064 + t + 50 + r) * 256 + n] = (bf16_t)(acc[ni][r] + bia);
    } else if constexpr (MODE == 2) {
      const int b = mb / 4000, t = mb - b * 4000;
      const int h = n >> 5, dv = n & 31;
      bf16_t* O = (bf16_t*)Out + ((size_t)((b * 8 + h) * 32 + dv)) * 4064 + t + 50;
      unsigned short e0 = bbits((bf16_t)(acc[ni][0] + bia));
      unsigned short e1 = bbits((bf16_t)(acc[ni][1] + bia));
      unsigned short e2 = bbits((bf16_t)(acc[ni][2] + bia));
      unsigned short e3 = bbits((bf16_t)(acc[ni][3] + bia));
      unsigned* O32 = (unsigned*)O;     // (t+50) even -> 4B aligned
      O32[0] = (unsigned)e0 | ((unsigned)e1 << 16);
      O32[1] = (unsigned)e2 | ((unsigned)e3 << 16);
    } else {
      float* O = (float*)Out;
#pragma unroll
      for (int r = 0; r < 4; ++r)
        O[(size_t)(mb + r) * 256 + n] = acc[ni][r] + bia;
    }
  }
}

// ---- fill replicate-pad edges + zero tails for kb and vt (nb batches) ----
__global__ void fill_edges(bf16_t* __restrict__ kb, bf16_t* __restrict__ vt, int nb) {
  const int idx = blockIdx.x * 256 + threadIdx.x;
  const int kcnt = nb * 64 * 256;
  if (idx < kcnt) {                    // kb: [nb][4064][256]
    const int b  = idx >> 14;
    const int pp = (idx >> 8) & 63;    // 0..63
    const int nn = idx & 255;
    const int p  = (pp < 50) ? pp : pp + 4000;   // [0,50) and [4050,4064)
    bf16_t v = (pp < 50) ? kb[((size_t)b * 4064 + 50) * 256 + nn] : (bf16_t)0.f;
    kb[((size_t)b * 4064 + p) * 256 + nn] = v;
  } else {                             // vt: [nb*8][32][4064]
    const int j  = idx - kcnt;
    const int bh = j >> 11;
    const int dv = (j >> 6) & 31;
    const int pp = j & 63;
    const int p  = (pp < 50) ? pp : pp + 4000;
    bf16_t v = (pp < 50) ? vt[((size_t)bh * 32 + dv) * 4064 + 50] : (bf16_t)0.f;
    vt[((size_t)bh * 32 + dv) * 4064 + p] = v;
  }
}

// ---- windowed attention: one block per (b',h,window), 7 waves = 7 row-strips ----
// Chunked: per 32-col chunk {2x QK MFMA -> exp -> 16x32 LDS bounce -> PV 3 MFMA}.
// No cross-lane ops, no barriers; denom via E@ones; normalize after PV.
__global__ __launch_bounds__(448)
void attn_win(const bf16_t* __restrict__ qb, const bf16_t* __restrict__ kb,
              const bf16_t* __restrict__ vt, bf16_t* __restrict__ ao) {
  const int blk = blockIdx.x;
  const int n = blk % 40;
  const int h = (blk / 40) & 7;
  const int b = blk / 320;
  const int wv = threadIdx.x >> 6;     // strip 0..6, rows i in [50+16wv, 66+16wv)
  const int lane = threadIdx.x & 63;
  const int lo = lane & 15, hi = lane >> 4;

  __shared__ __align__(16) bf16_t E[7][16][40];  // per-wave 16x32 chunk (pad 40)

  const int i0 = 50 + 16 * wv;
  int jtmax = (65 + 16 * wv) >> 4;     // last 16-tile with any unmasked element
  if (jtmax > 9) jtmax = 9;
  const int reach = jtmax * 16 + 16;

  // Q fragment (pre-scaled by 1/sqrt(200)): row lo -> token t = n*100+16wv+lo
  int tq = n * 100 + 16 * wv + lo;
  if (tq > 3999) tq = 3999;            // rows i>=150 are discarded at store
  const bf16x8 qf = *(const bf16x8*)&qb[((size_t)b * 4000 + tq) * 256 + h * 32 + hi * 8];

  const f32x4 zero = {0.f, 0.f, 0.f, 0.f};
  bf16x8 onesf;
#pragma unroll
  for (int u = 0; u < 8; ++u) onesf[u] = (bf16_t)1.0f;

  f32x4 o0 = zero, o1 = zero, sm = zero;
  const size_t vbase = ((size_t)((b * 8 + h) * 32)) * 4064 + n * 100;
  const size_t kbase = ((size_t)(b * 4064 + n * 100)) * 256 + h * 32 + hi * 8;
  const int dbase = i0 + hi * 4 - lo;  // d = dbase + r - 16*jt

#pragma unroll
  for (int kt = 0; kt < 5; ++kt) if (kt * 32 < reach) {
    // two score tiles -> E chunk [16][32]
#pragma unroll
    for (int half = 0; half < 2; ++half) {
      const int jt = kt * 2 + half;
      if (jt <= jtmax) {
        const bf16x8 kf = *(const bf16x8*)&kb[kbase + (size_t)(jt * 16 + lo) * 256];
        const f32x4 s = MFMA16(qf, kf, zero);
#pragma unroll
        for (int r = 0; r < 4; ++r) {
          const int d = dbase + r - jt * 16;
          const float df = (float)d;
          float c = __builtin_amdgcn_rcpf(__builtin_fmaf(0.25f * df, df, 1.f));
          c = (d == 0) ? 0.f : c;      // eye-mask: diagonal score -> 0 -> e=1
          float e = __expf(s[r] * c);
          e = (d < 0) ? 0.f : e;       // causal mask
          E[wv][hi * 4 + r][half * 16 + lo] = (bf16_t)e;
        }
      } else {
#pragma unroll
        for (int r = 0; r < 4; ++r)
          E[wv][hi * 4 + r][half * 16 + lo] = (bf16_t)0.f;
      }
    }
    // PV + denom for this 32-col chunk (wave-private LDS, in-order DS)
    const bf16x8 pf = *(const bf16x8*)&E[wv][lo][hi * 8];
    const bf16x8 v0 = *(const bf16x8*)&vt[vbase + (size_t)lo * 4064 + kt * 32 + hi * 8];
    const bf16x8 v1 = *(const bf16x8*)&vt[vbase + (size_t)(16 + lo) * 4064 + kt * 32 + hi * 8];
    o0 = MFMA16(pf, v0, o0);
    o1 = MFMA16(pf, v1, o1);
    sm = MFMA16(pf, onesf, sm);
  }

  // store central rows (i in [50,150)): out = o * rcp(rowsum); rowsum >= 1
#pragma unroll
  for (int r = 0; r < 4; ++r) {
    const int i = i0 + hi * 4 + r;
    if (i < 150) {
      const float ri = __builtin_amdgcn_rcpf(sm[r]);
      const int t = n * 100 + i - 50;
      bf16_t* op = &ao[((size_t)b * 4000 + t) * 256 + h * 32];
      op[lo]      = (bf16_t)(o0[r] * ri);
      op[16 + lo] = (bf16_t)(o1[r] * ri);
    }
  }
}

// ---------------------------------------------------------------------------
extern "C" void kernel_launch(void* const* d_in, const int* in_sizes, int n_in,
                              void* d_out, int out_size, void* d_ws, size_t ws_size,
                              hipStream_t stream) {
  (void)in_sizes; (void)n_in; (void)out_size;
  const float* query = (const float*)d_in[0];
  const float* key   = (const float*)d_in[1];
  const float* value = (const float*)d_in[2];
  const float* Wq = (const float*)d_in[3];
  const float* bq = (const float*)d_in[4];
  const float* Wk = (const float*)d_in[5];
  const float* bk = (const float*)d_in[6];
  const float* Wv = (const float*)d_in[7];
  const float* bv = (const float*)d_in[8];
  const float* Wo = (const float*)d_in[9];
  const float* bo = (const float*)d_in[10];

  // pick largest batch chunk bc that fits ws_size:
  // bytes(bc) = 524288 (wt) + bc * 8,257,536 (qb+kb+vt+ao per batch)
  int bc = 8;
  while (bc > 1 && 524288ull + (unsigned long long)bc * 8257536ull > (unsigned long long)ws_size)
    bc >>= 1;

  bf16_t* wt = (bf16_t*)d_ws;                           // 4 * 65536
  bf16_t* qb = wt + 4 * 65536;                          // bc*4000*256
  bf16_t* kb = qb + (size_t)bc * 4000 * 256;            // bc*4064*256
  bf16_t* vt = kb + (size_t)bc * 4064 * 256;            // bc*8*32*4064
  bf16_t* ao = vt + (size_t)bc * 8 * 32 * 4064;         // bc*4000*256

  prep_weights<<<256, 256, 0, stream>>>(Wq, Wk, Wv, Wo, wt);

  const float qscale = 0.07071067811865475f;  // 1/sqrt(200) folded into qb

  for (int b0 = 0; b0 < 8; b0 += bc) {
    const int M = bc * 4000;
    const int mblk = (M + 63) / 64;
    const float* qx = query + (size_t)b0 * 4000 * 256;
    const float* kx = key   + (size_t)b0 * 4000 * 256;
    const float* vx = value + (size_t)b0 * 4000 * 256;
    float* ox = (float*)d_out + (size_t)b0 * 4000 * 256;

    gemm256<0><<<dim3(mblk), 512, 0, stream>>>(qx, wt + 0 * 65536, bq, qb, M, qscale);
    gemm256<1><<<dim3(mblk), 512, 0, stream>>>(kx, wt + 1 * 65536, bk, kb, M, 1.f);
    gemm256<2><<<dim3(mblk), 512, 0, stream>>>(vx, wt + 2 * 65536, bv, vt, M, 1.f);
    fill_edges<<<bc * 128, 256, 0, stream>>>(kb, vt, bc);
    attn_win<<<bc * 320, 448, 0, stream>>>(qb, kb, vt, ao);
    gemm256<3><<<dim3(mblk), 512, 0, stream>>>(ao, wt + 3 * 65536, bo, ox, M, 1.f);
  }
}

// Round 7
// 105.168 us; speedup vs baseline: 1.1105x; 1.0096x over previous
//
#include <hip/hip_runtime.h>

// ---------------------------------------------------------------------------
// MultiHeadAttentionWindow: B=8 K=4000 D=256 H=8 DQ=DV=32 WIN=200 PAD=50 STEP=100
// Pipeline (batch chunk bc from ws_size):
//   prep_weights : Wt[n][k] = bf16(W[k][n]) for Wq,Wk,Wv,Wo   (once)
//   per chunk:
//     proj_gemm  : merged q/k/v projections (grid.y = mode 0/1/2)
//     fill_edges : replicate-pad edges, zero tails
//     attn_win   : causal cauchy softmax windows, rows 50..149
//     out_gemm   : out = ao @ Wo + bo (fp32)
// Round-7 GEMM structure (replaces 8-barrier-pair K-loop):
//   - whole B (256x256 bf16 = 128KB) staged in LDS ONCE, XOR-swizzled
//     (byte ^= (row&7)<<4) for even-bank ds_read_b128 fragments
//   - A in registers (16 rows/wave, 8 waves = 128-row block), fetched once
//   - K-loop: 128 MFMA + 128 ds_read per wave, ZERO barriers/re-staging
// ---------------------------------------------------------------------------

typedef __bf16 bf16_t;
typedef __bf16 bf16x8 __attribute__((ext_vector_type(8)));
typedef float  f32x4  __attribute__((ext_vector_type(4)));

#define MFMA16(a, b, c) __builtin_amdgcn_mfma_f32_16x16x32_bf16((a), (b), (c), 0, 0, 0)

static __device__ __forceinline__ bf16x8 cvt8(float4 a, float4 b) {
  bf16x8 r;
  r[0] = (bf16_t)a.x; r[1] = (bf16_t)a.y; r[2] = (bf16_t)a.z; r[3] = (bf16_t)a.w;
  r[4] = (bf16_t)b.x; r[5] = (bf16_t)b.y; r[6] = (bf16_t)b.z; r[7] = (bf16_t)b.w;
  return r;
}

static __device__ __forceinline__ unsigned short bbits(bf16_t v) {
  union { bf16_t b; unsigned short u; } c; c.b = v; return c.u;
}

// ---- weight transpose + bf16 convert: Wt[n][k] = bf16(W[k][n]), 4 matrices ----
__global__ __launch_bounds__(256)
void prep_weights(const float* __restrict__ Wq, const float* __restrict__ Wk,
                  const float* __restrict__ Wv, const float* __restrict__ Wo,
                  bf16_t* __restrict__ wt) {
  const int mat  = blockIdx.x >> 6;
  const int tile = blockIdx.x & 63;
  const int kt = (tile >> 3) * 32, nt = (tile & 7) * 32;
  const float* W = (mat == 0) ? Wq : (mat == 1) ? Wk : (mat == 2) ? Wv : Wo;
  __shared__ float t[32][33];
  const int tx = threadIdx.x & 31, ty = threadIdx.x >> 5;  // ty 0..7
#pragma unroll
  for (int i = 0; i < 32; i += 8)
    t[ty + i][tx] = W[(size_t)(kt + ty + i) * 256 + nt + tx];
  __syncthreads();
  bf16_t* dst = wt + (size_t)mat * 65536;
#pragma unroll
  for (int i = 0; i < 32; i += 8)
    dst[(size_t)(nt + ty + i) * 256 + kt + tx] = (bf16_t)t[tx][ty + i];
}

// ---- helper: stage 256x256 bf16 Wt slab into LDS, XOR-swizzled ----
// lds[row][colb ^ ((row&7)<<4)] = W[row][colb]  (byte addressing, colb mult of 16)
static __device__ __forceinline__ void stage_B(const bf16_t* __restrict__ W,
                                               bf16_t* lb, int tid) {
#pragma unroll
  for (int i = 0; i < 16; ++i) {
    const int g    = tid + i * 512;        // 16B-chunk id 0..8191
    const int row  = g >> 5;
    const int colb = (g & 31) << 4;        // byte col within row (0..496)
    const bf16x8 w = *(const bf16x8*)&W[row * 256 + (colb >> 1)];
    *(bf16x8*)((char*)lb + row * 512 + (colb ^ ((row & 7) << 4))) = w;
  }
}

// ---- merged projection GEMM: [M x 256] x [256 x 256] + bias ----
// grid (mblk, 3); mode = blockIdx.y: 0 -> qb (row-major, *qscale),
// 1 -> kb (rows b*4064+t+50), 2 -> vt (transposed [bh*32+dv][p]).
__global__ __launch_bounds__(512)
void proj_gemm(const float* __restrict__ qx, const float* __restrict__ kx,
               const float* __restrict__ vx, const bf16_t* __restrict__ wt,
               const float* __restrict__ bq, const float* __restrict__ bk,
               const float* __restrict__ bv,
               bf16_t* __restrict__ qb, bf16_t* __restrict__ kb,
               bf16_t* __restrict__ vt, int M, float qscale) {
  const int mode = blockIdx.y;
  const float* X    = (mode == 0) ? qx : (mode == 1) ? kx : vx;
  const float* bias = (mode == 0) ? bq : (mode == 1) ? bk : bv;

  __shared__ bf16_t lb[65536];             // 128 KB: whole B, swizzled
  const int tid = threadIdx.x;
  stage_B(wt + (size_t)mode * 65536, lb, tid);

  const int lane = tid & 63, wv = tid >> 6;
  const int lo = lane & 15, hi = lane >> 4;
  const int m0 = blockIdx.x * 128;
  int ar = m0 + wv * 16 + lo; if (ar >= M) ar = M - 1;

  // A fragments into registers: 8 K-chunks x (16B fp32 x2 -> bf16x8)
  bf16x8 areg[8];
#pragma unroll
  for (int kk = 0; kk < 8; ++kk) {
    const float* ap = X + (size_t)ar * 256 + kk * 32 + hi * 8;
    areg[kk] = cvt8(((const float4*)ap)[0], ((const float4*)ap)[1]);
  }
  __syncthreads();                         // B staged

  f32x4 acc[16] = {};
#pragma unroll
  for (int kk = 0; kk < 8; ++kk) {
#pragma unroll
    for (int ni = 0; ni < 16; ++ni) {
      const int row = ni * 16 + lo;
      const int off = row * 512 + (((kk * 64) + hi * 16) ^ ((row & 7) << 4));
      const bf16x8 bfrag = *(const bf16x8*)((const char*)lb + off);
      acc[ni] = MFMA16(areg[kk], bfrag, acc[ni]);
    }
  }

  // epilogue: C/D layout col = lane&15, row = (lane>>4)*4 + r  [m89-verified]
  const int mb = m0 + wv * 16 + hi * 4;    // 4-aligned
  if (mb >= M) return;
#pragma unroll
  for (int ni = 0; ni < 16; ++ni) {
    const int n = ni * 16 + lo;
    const float bia = bias[n];
    if (mode == 0) {
#pragma unroll
      for (int r = 0; r < 4; ++r)
        qb[(size_t)(mb + r) * 256 + n] = (bf16_t)((acc[ni][r] + bia) * qscale);
    } else if (mode == 1) {
      const int b = mb / 4000, t = mb - b * 4000;
#pragma unroll
      for (int r = 0; r < 4; ++r)
        kb[((size_t)b * 4064 + t + 50 + r) * 256 + n] = (bf16_t)(acc[ni][r] + bia);
    } else {
      const int b = mb / 4000, t = mb - b * 4000;
      const int h = n >> 5, dv = n & 31;
      bf16_t* O = vt + ((size_t)((b * 8 + h) * 32 + dv)) * 4064 + t + 50;
      unsigned short e0 = bbits((bf16_t)(acc[ni][0] + bia));
      unsigned short e1 = bbits((bf16_t)(acc[ni][1] + bia));
      unsigned short e2 = bbits((bf16_t)(acc[ni][2] + bia));
      unsigned short e3 = bbits((bf16_t)(acc[ni][3] + bia));
      unsigned* O32 = (unsigned*)O;        // (t+50) even -> 4B aligned
      O32[0] = (unsigned)e0 | ((unsigned)e1 << 16);
      O32[1] = (unsigned)e2 | ((unsigned)e3 << 16);
    }
  }
}

// ---- output GEMM: ao[M x 256] (bf16) x Wo^T + bo -> fp32 out ----
__global__ __launch_bounds__(512)
void out_gemm(const bf16_t* __restrict__ ao, const bf16_t* __restrict__ wt,
              const float* __restrict__ bias, float* __restrict__ Out, int M) {
  __shared__ bf16_t lb[65536];
  const int tid = threadIdx.x;
  stage_B(wt, lb, tid);

  const int lane = tid & 63, wv = tid >> 6;
  const int lo = lane & 15, hi = lane >> 4;
  const int m0 = blockIdx.x * 128;
  int ar = m0 + wv * 16 + lo; if (ar >= M) ar = M - 1;

  bf16x8 areg[8];
#pragma unroll
  for (int kk = 0; kk < 8; ++kk)
    areg[kk] = *(const bf16x8*)&ao[(size_t)ar * 256 + kk * 32 + hi * 8];
  __syncthreads();

  f32x4 acc[16] = {};
#pragma unroll
  for (int kk = 0; kk < 8; ++kk) {
#pragma unroll
    for (int ni = 0; ni < 16; ++ni) {
      const int row = ni * 16 + lo;
      const int off = row * 512 + (((kk * 64) + hi * 16) ^ ((row & 7) << 4));
      const bf16x8 bfrag = *(const bf16x8*)((const char*)lb + off);
      acc[ni] = MFMA16(areg[kk], bfrag, acc[ni]);
    }
  }

  const int mb = m0 + wv * 16 + hi * 4;
  if (mb >= M) return;
#pragma unroll
  for (int ni = 0; ni < 16; ++ni) {
    const int n = ni * 16 + lo;
    const float bia = bias[n];
#pragma unroll
    for (int r = 0; r < 4; ++r)
      Out[(size_t)(mb + r) * 256 + n] = acc[ni][r] + bia;
  }
}

// ---- fill replicate-pad edges + zero tails for kb and vt (nb batches) ----
__global__ void fill_edges(bf16_t* __restrict__ kb, bf16_t* __restrict__ vt, int nb) {
  const int idx = blockIdx.x * 256 + threadIdx.x;
  const int kcnt = nb * 64 * 256;
  if (idx < kcnt) {                    // kb: [nb][4064][256]
    const int b  = idx >> 14;
    const int pp = (idx >> 8) & 63;    // 0..63
    const int nn = idx & 255;
    const int p  = (pp < 50) ? pp : pp + 4000;   // [0,50) and [4050,4064)
    bf16_t v = (pp < 50) ? kb[((size_t)b * 4064 + 50) * 256 + nn] : (bf16_t)0.f;
    kb[((size_t)b * 4064 + p) * 256 + nn] = v;
  } else {                             // vt: [nb*8][32][4064]
    const int j  = idx - kcnt;
    const int bh = j >> 11;
    const int dv = (j >> 6) & 31;
    const int pp = j & 63;
    const int p  = (pp < 50) ? pp : pp + 4000;
    bf16_t v = (pp < 50) ? vt[((size_t)bh * 32 + dv) * 4064 + 50] : (bf16_t)0.f;
    vt[((size_t)bh * 32 + dv) * 4064 + p] = v;
  }
}

// ---- windowed attention: one block per (b',h,window), 7 waves = 7 row-strips ----
// Chunked: per 32-col chunk {2x QK MFMA -> exp -> 16x32 LDS bounce -> PV 3 MFMA}.
// No cross-lane ops, no barriers; denom via E@ones; normalize after PV.
__global__ __launch_bounds__(448)
void attn_win(const bf16_t* __restrict__ qb, const bf16_t* __restrict__ kb,
              const bf16_t* __restrict__ vt, bf16_t* __restrict__ ao) {
  const int blk = blockIdx.x;
  const int n = blk % 40;
  const int h = (blk / 40) & 7;
  const int b = blk / 320;
  const int wv = threadIdx.x >> 6;     // strip 0..6, rows i in [50+16wv, 66+16wv)
  const int lane = threadIdx.x & 63;
  const int lo = lane & 15, hi = lane >> 4;

  __shared__ __align__(16) bf16_t E[7][16][40];  // per-wave 16x32 chunk (pad 40)

  const int i0 = 50 + 16 * wv;
  int jtmax = (65 + 16 * wv) >> 4;     // last 16-tile with any unmasked element
  if (jtmax > 9) jtmax = 9;
  const int reach = jtmax * 16 + 16;

  // Q fragment (pre-scaled by 1/sqrt(200)): row lo -> token t = n*100+16wv+lo
  int tq = n * 100 + 16 * wv + lo;
  if (tq > 3999) tq = 3999;            // rows i>=150 are discarded at store
  const bf16x8 qf = *(const bf16x8*)&qb[((size_t)b * 4000 + tq) * 256 + h * 32 + hi * 8];

  const f32x4 zero = {0.f, 0.f, 0.f, 0.f};
  bf16x8 onesf;
#pragma unroll
  for (int u = 0; u < 8; ++u) onesf[u] = (bf16_t)1.0f;

  f32x4 o0 = zero, o1 = zero, sm = zero;
  const size_t vbase = ((size_t)((b * 8 + h) * 32)) * 4064 + n * 100;
  const size_t kbase = ((size_t)(b * 4064 + n * 100)) * 256 + h * 32 + hi * 8;
  const int dbase = i0 + hi * 4 - lo;  // d = dbase + r - 16*jt

#pragma unroll
  for (int kt = 0; kt < 5; ++kt) if (kt * 32 < reach) {
    // two score tiles -> E chunk [16][32]
#pragma unroll
    for (int half = 0; half < 2; ++half) {
      const int jt = kt * 2 + half;
      if (jt <= jtmax) {
        const bf16x8 kf = *(const bf16x8*)&kb[kbase + (size_t)(jt * 16 + lo) * 256];
        const f32x4 s = MFMA16(qf, kf, zero);
#pragma unroll
        for (int r = 0; r < 4; ++r) {
          const int d = dbase + r - jt * 16;
          const float df = (float)d;
          float c = __builtin_amdgcn_rcpf(__builtin_fmaf(0.25f * df, df, 1.f));
          c = (d == 0) ? 0.f : c;      // eye-mask: diagonal score -> 0 -> e=1
          float e = __expf(s[r] * c);
          e = (d < 0) ? 0.f : e;       // causal mask
          E[wv][hi * 4 + r][half * 16 + lo] = (bf16_t)e;
        }
      } else {
#pragma unroll
        for (int r = 0; r < 4; ++r)
          E[wv][hi * 4 + r][half * 16 + lo] = (bf16_t)0.f;
      }
    }
    // PV + denom for this 32-col chunk (wave-private LDS, in-order DS)
    const bf16x8 pf = *(const bf16x8*)&E[wv][lo][hi * 8];
    const bf16x8 v0 = *(const bf16x8*)&vt[vbase + (size_t)lo * 4064 + kt * 32 + hi * 8];
    const bf16x8 v1 = *(const bf16x8*)&vt[vbase + (size_t)(16 + lo) * 4064 + kt * 32 + hi * 8];
    o0 = MFMA16(pf, v0, o0);
    o1 = MFMA16(pf, v1, o1);
    sm = MFMA16(pf, onesf, sm);
  }

  // store central rows (i in [50,150)): out = o * rcp(rowsum); rowsum >= 1
#pragma unroll
  for (int r = 0; r < 4; ++r) {
    const int i = i0 + hi * 4 + r;
    if (i < 150) {
      const float ri = __builtin_amdgcn_rcpf(sm[r]);
      const int t = n * 100 + i - 50;
      bf16_t* op = &ao[((size_t)b * 4000 + t) * 256 + h * 32];
      op[lo]      = (bf16_t)(o0[r] * ri);
      op[16 + lo] = (bf16_t)(o1[r] * ri);
    }
  }
}

// ---------------------------------------------------------------------------
extern "C" void kernel_launch(void* const* d_in, const int* in_sizes, int n_in,
                              void* d_out, int out_size, void* d_ws, size_t ws_size,
                              hipStream_t stream) {
  (void)in_sizes; (void)n_in; (void)out_size;
  const float* query = (const float*)d_in[0];
  const float* key   = (const float*)d_in[1];
  const float* value = (const float*)d_in[2];
  const float* Wq = (const float*)d_in[3];
  const float* bq = (const float*)d_in[4];
  const float* Wk = (const float*)d_in[5];
  const float* bk = (const float*)d_in[6];
  const float* Wv = (const float*)d_in[7];
  const float* bv = (const float*)d_in[8];
  const float* Wo = (const float*)d_in[9];
  const float* bo = (const float*)d_in[10];

  // pick largest batch chunk bc that fits ws_size:
  // bytes(bc) = 524288 (wt) + bc * 8,257,536 (qb+kb+vt+ao per batch)
  int bc = 8;
  while (bc > 1 && 524288ull + (unsigned long long)bc * 8257536ull > (unsigned long long)ws_size)
    bc >>= 1;

  bf16_t* wt = (bf16_t*)d_ws;                           // 4 * 65536
  bf16_t* qb = wt + 4 * 65536;                          // bc*4000*256
  bf16_t* kb = qb + (size_t)bc * 4000 * 256;            // bc*4064*256
  bf16_t* vt = kb + (size_t)bc * 4064 * 256;            // bc*8*32*4064
  bf16_t* ao = vt + (size_t)bc * 8 * 32 * 4064;         // bc*4000*256

  prep_weights<<<256, 256, 0, stream>>>(Wq, Wk, Wv, Wo, wt);

  const float qscale = 0.07071067811865475f;  // 1/sqrt(200) folded into qb

  for (int b0 = 0; b0 < 8; b0 += bc) {
    const int M = bc * 4000;
    const int mblk = (M + 127) / 128;
    const float* qx = query + (size_t)b0 * 4000 * 256;
    const float* kx = key   + (size_t)b0 * 4000 * 256;
    const float* vx = value + (size_t)b0 * 4000 * 256;
    float* ox = (float*)d_out + (size_t)b0 * 4000 * 256;

    proj_gemm<<<dim3(mblk, 3), 512, 0, stream>>>(qx, kx, vx, wt, bq, bk, bv,
                                                 qb, kb, vt, M, qscale);
    fill_edges<<<bc * 128, 256, 0, stream>>>(kb, vt, bc);
    attn_win<<<bc * 320, 448, 0, stream>>>(qb, kb, vt, ao);
    out_gemm<<<dim3(mblk), 512, 0, stream>>>(ao, wt + 3 * 65536, bo, ox, M);
  }
}

// Round 8
// 97.238 us; speedup vs baseline: 1.2011x; 1.0816x over previous
//
#include <hip/hip_runtime.h>

// ---------------------------------------------------------------------------
// MultiHeadAttentionWindow: B=8 K=4000 D=256 H=8 DQ=DV=32 WIN=200 PAD=50 STEP=100
// Pipeline (batch chunk bc from ws_size):
//   prep_weights : Wt[n][k] = bf16(W[k][n]) for Wq,Wk,Wv,Wo   (once)
//   per chunk:
//     proj_gemm  : merged q/k/v projections (grid.y = mode 0/1/2)
//     fill_edges : replicate-pad edges, zero tails
//     attn_win   : causal cauchy softmax windows, rows 50..149
//     out_gemm   : out = ao @ Wo + bo (fp32)
// Round-8 GEMM: BM=64 x BN=256(full-N, A fetched once) x BK=32, 4 waves,
//   wave-tile 64x64 (4x4 acc, 8 ds_read_b128 : 16 MFMA), stride-40 LDS rows.
//   Reverts r7's whole-B-in-LDS (128KB -> 1 blk/CU, 8-way bank conflicts).
// ---------------------------------------------------------------------------

typedef __bf16 bf16_t;
typedef __bf16 bf16x8 __attribute__((ext_vector_type(8)));
typedef float  f32x4  __attribute__((ext_vector_type(4)));

#define MFMA16(a, b, c) __builtin_amdgcn_mfma_f32_16x16x32_bf16((a), (b), (c), 0, 0, 0)

static __device__ __forceinline__ bf16x8 cvt8(float4 a, float4 b) {
  bf16x8 r;
  r[0] = (bf16_t)a.x; r[1] = (bf16_t)a.y; r[2] = (bf16_t)a.z; r[3] = (bf16_t)a.w;
  r[4] = (bf16_t)b.x; r[5] = (bf16_t)b.y; r[6] = (bf16_t)b.z; r[7] = (bf16_t)b.w;
  return r;
}

static __device__ __forceinline__ unsigned short bbits(bf16_t v) {
  union { bf16_t b; unsigned short u; } c; c.b = v; return c.u;
}

// ---- weight transpose + bf16 convert: Wt[n][k] = bf16(W[k][n]), 4 matrices ----
__global__ __launch_bounds__(256)
void prep_weights(const float* __restrict__ Wq, const float* __restrict__ Wk,
                  const float* __restrict__ Wv, const float* __restrict__ Wo,
                  bf16_t* __restrict__ wt) {
  const int mat  = blockIdx.x >> 6;
  const int tile = blockIdx.x & 63;
  const int kt = (tile >> 3) * 32, nt = (tile & 7) * 32;
  const float* W = (mat == 0) ? Wq : (mat == 1) ? Wk : (mat == 2) ? Wv : Wo;
  __shared__ float t[32][33];
  const int tx = threadIdx.x & 31, ty = threadIdx.x >> 5;  // ty 0..7
#pragma unroll
  for (int i = 0; i < 32; i += 8)
    t[ty + i][tx] = W[(size_t)(kt + ty + i) * 256 + nt + tx];
  __syncthreads();
  bf16_t* dst = wt + (size_t)mat * 65536;
#pragma unroll
  for (int i = 0; i < 32; i += 8)
    dst[(size_t)(nt + ty + i) * 256 + kt + tx] = (bf16_t)t[tx][ty + i];
}

// ---- merged projection GEMM: [M x 256] x [256 x 256] + bias ----
// grid (mblk, 3); mode = blockIdx.y: 0 -> qb (row-major, *qscale),
// 1 -> kb (rows b*4064+t+50), 2 -> vt (transposed [bh*32+dv][p]).
// Block: 64 rows x 256 cols, 4 waves, each wave 64x64 (4x4 acc frags).
__global__ __launch_bounds__(256)
void proj_gemm(const float* __restrict__ qx, const float* __restrict__ kx,
               const float* __restrict__ vx, const bf16_t* __restrict__ wt,
               const float* __restrict__ bq, const float* __restrict__ bk,
               const float* __restrict__ bv,
               bf16_t* __restrict__ qb, bf16_t* __restrict__ kb,
               bf16_t* __restrict__ vt, int M, float qscale) {
  const int mode = blockIdx.y;
  const float* X    = (mode == 0) ? qx : (mode == 1) ? kx : vx;
  const float* bias = (mode == 0) ? bq : (mode == 1) ? bk : bv;
  const bf16_t* W   = wt + (size_t)mode * 65536;

  __shared__ bf16_t la[64 * 40];    // A tile 64x32, stride 40 (80B rows)
  __shared__ bf16_t lb[256 * 40];   // B tile 256x32, stride 40
  const int tid  = threadIdx.x;
  const int lane = tid & 63;
  const int wv   = tid >> 6;        // 0..3: wave col group (wn = wv*64)
  const int lo   = lane & 15, hi = lane >> 4;
  const int m0   = blockIdx.x * 64;
  int ar = m0 + (tid >> 2); if (ar >= M) ar = M - 1;  // A staging row
  const int acg  = (tid & 3) * 8;   // A staging col group (8 fp32)
  const int brow = tid >> 2;        // B staging base row (0..63), +64*rr
  const int bcg  = (tid & 3) * 8;   // B staging col group (8 bf16)

  f32x4 acc[4][4] = {};

  for (int kk = 0; kk < 256; kk += 32) {
    // stage A (64x32 fp32 -> bf16): 4 threads/row, 8 cols each
    {
      const float* ap = X + (size_t)ar * 256 + kk + acg;
      *(bf16x8*)&la[(tid >> 2) * 40 + acg] =
          cvt8(((const float4*)ap)[0], ((const float4*)ap)[1]);
    }
    // stage B (256x32 bf16): 4 passes of 64 rows
#pragma unroll
    for (int rr = 0; rr < 4; ++rr) {
      const int row = brow + rr * 64;
      *(bf16x8*)&lb[row * 40 + bcg] =
          *(const bf16x8*)&W[(size_t)row * 256 + kk + bcg];
    }
    __syncthreads();

    bf16x8 af[4], bfv[4];
#pragma unroll
    for (int mi = 0; mi < 4; ++mi)
      af[mi] = *(const bf16x8*)&la[(mi * 16 + lo) * 40 + hi * 8];
#pragma unroll
    for (int ni = 0; ni < 4; ++ni)
      bfv[ni] = *(const bf16x8*)&lb[(wv * 64 + ni * 16 + lo) * 40 + hi * 8];
#pragma unroll
    for (int mi = 0; mi < 4; ++mi)
#pragma unroll
      for (int ni = 0; ni < 4; ++ni)
        acc[mi][ni] = MFMA16(af[mi], bfv[ni], acc[mi][ni]);
    __syncthreads();
  }

  // epilogue: C/D layout col = lane&15, row = (lane>>4)*4 + r  [m89-verified]
#pragma unroll
  for (int mi = 0; mi < 4; ++mi) {
    const int mb = m0 + mi * 16 + hi * 4;   // 4-aligned; M % 4 == 0
    if (mb >= M) continue;
#pragma unroll
    for (int ni = 0; ni < 4; ++ni) {
      const int n = wv * 64 + ni * 16 + lo;
      const float bia = bias[n];
      if (mode == 0) {
#pragma unroll
        for (int r = 0; r < 4; ++r)
          qb[(size_t)(mb + r) * 256 + n] = (bf16_t)((acc[mi][ni][r] + bia) * qscale);
      } else if (mode == 1) {
        const int b = mb / 4000, t = mb - b * 4000;
#pragma unroll
        for (int r = 0; r < 4; ++r)
          kb[((size_t)b * 4064 + t + 50 + r) * 256 + n] = (bf16_t)(acc[mi][ni][r] + bia);
      } else {
        const int b = mb / 4000, t = mb - b * 4000;
        const int h = n >> 5, dv = n & 31;
        bf16_t* O = vt + ((size_t)((b * 8 + h) * 32 + dv)) * 4064 + t + 50;
        unsigned short e0 = bbits((bf16_t)(acc[mi][ni][0] + bia));
        unsigned short e1 = bbits((bf16_t)(acc[mi][ni][1] + bia));
        unsigned short e2 = bbits((bf16_t)(acc[mi][ni][2] + bia));
        unsigned short e3 = bbits((bf16_t)(acc[mi][ni][3] + bia));
        unsigned* O32 = (unsigned*)O;       // (t+50) even -> 4B aligned
        O32[0] = (unsigned)e0 | ((unsigned)e1 << 16);
        O32[1] = (unsigned)e2 | ((unsigned)e3 << 16);
      }
    }
  }
}

// ---- output GEMM: ao[M x 256] (bf16) x Wo^T + bo -> fp32 out ----
__global__ __launch_bounds__(256)
void out_gemm(const bf16_t* __restrict__ ao, const bf16_t* __restrict__ wt,
              const float* __restrict__ bias, float* __restrict__ Out, int M) {
  __shared__ bf16_t la[64 * 40];
  __shared__ bf16_t lb[256 * 40];
  const int tid  = threadIdx.x;
  const int lane = tid & 63;
  const int wv   = tid >> 6;
  const int lo   = lane & 15, hi = lane >> 4;
  const int m0   = blockIdx.x * 64;
  int ar = m0 + (tid >> 2); if (ar >= M) ar = M - 1;
  const int acg  = (tid & 3) * 8;
  const int brow = tid >> 2;
  const int bcg  = (tid & 3) * 8;

  f32x4 acc[4][4] = {};

  for (int kk = 0; kk < 256; kk += 32) {
    *(bf16x8*)&la[(tid >> 2) * 40 + acg] =
        *(const bf16x8*)&ao[(size_t)ar * 256 + kk + acg];
#pragma unroll
    for (int rr = 0; rr < 4; ++rr) {
      const int row = brow + rr * 64;
      *(bf16x8*)&lb[row * 40 + bcg] =
          *(const bf16x8*)&wt[(size_t)row * 256 + kk + bcg];
    }
    __syncthreads();

    bf16x8 af[4], bfv[4];
#pragma unroll
    for (int mi = 0; mi < 4; ++mi)
      af[mi] = *(const bf16x8*)&la[(mi * 16 + lo) * 40 + hi * 8];
#pragma unroll
    for (int ni = 0; ni < 4; ++ni)
      bfv[ni] = *(const bf16x8*)&lb[(wv * 64 + ni * 16 + lo) * 40 + hi * 8];
#pragma unroll
    for (int mi = 0; mi < 4; ++mi)
#pragma unroll
      for (int ni = 0; ni < 4; ++ni)
        acc[mi][ni] = MFMA16(af[mi], bfv[ni], acc[mi][ni]);
    __syncthreads();
  }

#pragma unroll
  for (int mi = 0; mi < 4; ++mi) {
    const int mb = m0 + mi * 16 + hi * 4;
    if (mb >= M) continue;
#pragma unroll
    for (int ni = 0; ni < 4; ++ni) {
      const int n = wv * 64 + ni * 16 + lo;
      const float bia = bias[n];
#pragma unroll
      for (int r = 0; r < 4; ++r)
        Out[(size_t)(mb + r) * 256 + n] = acc[mi][ni][r] + bia;
    }
  }
}

// ---- fill replicate-pad edges + zero tails for kb and vt (nb batches) ----
__global__ void fill_edges(bf16_t* __restrict__ kb, bf16_t* __restrict__ vt, int nb) {
  const int idx = blockIdx.x * 256 + threadIdx.x;
  const int kcnt = nb * 64 * 256;
  if (idx < kcnt) {                    // kb: [nb][4064][256]
    const int b  = idx >> 14;
    const int pp = (idx >> 8) & 63;    // 0..63
    const int nn = idx & 255;
    const int p  = (pp < 50) ? pp : pp + 4000;   // [0,50) and [4050,4064)
    bf16_t v = (pp < 50) ? kb[((size_t)b * 4064 + 50) * 256 + nn] : (bf16_t)0.f;
    kb[((size_t)b * 4064 + p) * 256 + nn] = v;
  } else {                             // vt: [nb*8][32][4064]
    const int j  = idx - kcnt;
    const int bh = j >> 11;
    const int dv = (j >> 6) & 31;
    const int pp = j & 63;
    const int p  = (pp < 50) ? pp : pp + 4000;
    bf16_t v = (pp < 50) ? vt[((size_t)bh * 32 + dv) * 4064 + 50] : (bf16_t)0.f;
    vt[((size_t)bh * 32 + dv) * 4064 + p] = v;
  }
}

// ---- windowed attention: one block per (b',h,window), 7 waves = 7 row-strips ----
// Chunked: per 32-col chunk {2x QK MFMA -> exp -> 16x32 LDS bounce -> PV 3 MFMA}.
// No cross-lane ops, no barriers; denom via E@ones; normalize after PV.
__global__ __launch_bounds__(448)
void attn_win(const bf16_t* __restrict__ qb, const bf16_t* __restrict__ kb,
              const bf16_t* __restrict__ vt, bf16_t* __restrict__ ao) {
  const int blk = blockIdx.x;
  const int n = blk % 40;
  const int h = (blk / 40) & 7;
  const int b = blk / 320;
  const int wv = threadIdx.x >> 6;     // strip 0..6, rows i in [50+16wv, 66+16wv)
  const int lane = threadIdx.x & 63;
  const int lo = lane & 15, hi = lane >> 4;

  __shared__ __align__(16) bf16_t E[7][16][40];  // per-wave 16x32 chunk (pad 40)

  const int i0 = 50 + 16 * wv;
  int jtmax = (65 + 16 * wv) >> 4;     // last 16-tile with any unmasked element
  if (jtmax > 9) jtmax = 9;
  const int reach = jtmax * 16 + 16;

  // Q fragment (pre-scaled by 1/sqrt(200)): row lo -> token t = n*100+16wv+lo
  int tq = n * 100 + 16 * wv + lo;
  if (tq > 3999) tq = 3999;            // rows i>=150 are discarded at store
  const bf16x8 qf = *(const bf16x8*)&qb[((size_t)b * 4000 + tq) * 256 + h * 32 + hi * 8];

  const f32x4 zero = {0.f, 0.f, 0.f, 0.f};
  bf16x8 onesf;
#pragma unroll
  for (int u = 0; u < 8; ++u) onesf[u] = (bf16_t)1.0f;

  f32x4 o0 = zero, o1 = zero, sm = zero;
  const size_t vbase = ((size_t)((b * 8 + h) * 32)) * 4064 + n * 100;
  const size_t kbase = ((size_t)(b * 4064 + n * 100)) * 256 + h * 32 + hi * 8;
  const int dbase = i0 + hi * 4 - lo;  // d = dbase + r - 16*jt

#pragma unroll
  for (int kt = 0; kt < 5; ++kt) if (kt * 32 < reach) {
    // two score tiles -> E chunk [16][32]
#pragma unroll
    for (int half = 0; half < 2; ++half) {
      const int jt = kt * 2 + half;
      if (jt <= jtmax) {
        const bf16x8 kf = *(const bf16x8*)&kb[kbase + (size_t)(jt * 16 + lo) * 256];
        const f32x4 s = MFMA16(qf, kf, zero);
#pragma unroll
        for (int r = 0; r < 4; ++r) {
          const int d = dbase + r - jt * 16;
          const float df = (float)d;
          float c = __builtin_amdgcn_rcpf(__builtin_fmaf(0.25f * df, df, 1.f));
          c = (d == 0) ? 0.f : c;      // eye-mask: diagonal score -> 0 -> e=1
          float e = __expf(s[r] * c);
          e = (d < 0) ? 0.f : e;       // causal mask
          E[wv][hi * 4 + r][half * 16 + lo] = (bf16_t)e;
        }
      } else {
#pragma unroll
        for (int r = 0; r < 4; ++r)
          E[wv][hi * 4 + r][half * 16 + lo] = (bf16_t)0.f;
      }
    }
    // PV + denom for this 32-col chunk (wave-private LDS, in-order DS)
    const bf16x8 pf = *(const bf16x8*)&E[wv][lo][hi * 8];
    const bf16x8 v0 = *(const bf16x8*)&vt[vbase + (size_t)lo * 4064 + kt * 32 + hi * 8];
    const bf16x8 v1 = *(const bf16x8*)&vt[vbase + (size_t)(16 + lo) * 4064 + kt * 32 + hi * 8];
    o0 = MFMA16(pf, v0, o0);
    o1 = MFMA16(pf, v1, o1);
    sm = MFMA16(pf, onesf, sm);
  }

  // store central rows (i in [50,150)): out = o * rcp(rowsum); rowsum >= 1
#pragma unroll
  for (int r = 0; r < 4; ++r) {
    const int i = i0 + hi * 4 + r;
    if (i < 150) {
      const float ri = __builtin_amdgcn_rcpf(sm[r]);
      const int t = n * 100 + i - 50;
      bf16_t* op = &ao[((size_t)b * 4000 + t) * 256 + h * 32];
      op[lo]      = (bf16_t)(o0[r] * ri);
      op[16 + lo] = (bf16_t)(o1[r] * ri);
    }
  }
}

// ---------------------------------------------------------------------------
extern "C" void kernel_launch(void* const* d_in, const int* in_sizes, int n_in,
                              void* d_out, int out_size, void* d_ws, size_t ws_size,
                              hipStream_t stream) {
  (void)in_sizes; (void)n_in; (void)out_size;
  const float* query = (const float*)d_in[0];
  const float* key   = (const float*)d_in[1];
  const float* value = (const float*)d_in[2];
  const float* Wq = (const float*)d_in[3];
  const float* bq = (const float*)d_in[4];
  const float* Wk = (const float*)d_in[5];
  const float* bk = (const float*)d_in[6];
  const float* Wv = (const float*)d_in[7];
  const float* bv = (const float*)d_in[8];
  const float* Wo = (const float*)d_in[9];
  const float* bo = (const float*)d_in[10];

  // pick largest batch chunk bc that fits ws_size:
  // bytes(bc) = 524288 (wt) + bc * 8,257,536 (qb+kb+vt+ao per batch)
  int bc = 8;
  while (bc > 1 && 524288ull + (unsigned long long)bc * 8257536ull > (unsigned long long)ws_size)
    bc >>= 1;

  bf16_t* wt = (bf16_t*)d_ws;                           // 4 * 65536
  bf16_t* qb = wt + 4 * 65536;                          // bc*4000*256
  bf16_t* kb = qb + (size_t)bc * 4000 * 256;            // bc*4064*256
  bf16_t* vt = kb + (size_t)bc * 4064 * 256;            // bc*8*32*4064
  bf16_t* ao = vt + (size_t)bc * 8 * 32 * 4064;         // bc*4000*256

  prep_weights<<<256, 256, 0, stream>>>(Wq, Wk, Wv, Wo, wt);

  const float qscale = 0.07071067811865475f;  // 1/sqrt(200) folded into qb

  for (int b0 = 0; b0 < 8; b0 += bc) {
    const int M = bc * 4000;
    const int mblk = (M + 63) / 64;
    const float* qx = query + (size_t)b0 * 4000 * 256;
    const float* kx = key   + (size_t)b0 * 4000 * 256;
    const float* vx = value + (size_t)b0 * 4000 * 256;
    float* ox = (float*)d_out + (size_t)b0 * 4000 * 256;

    proj_gemm<<<dim3(mblk, 3), 256, 0, stream>>>(qx, kx, vx, wt, bq, bk, bv,
                                                 qb, kb, vt, M, qscale);
    fill_edges<<<bc * 128, 256, 0, stream>>>(kb, vt, bc);
    attn_win<<<bc * 320, 448, 0, stream>>>(qb, kb, vt, ao);
    out_gemm<<<dim3(mblk), 256, 0, stream>>>(ao, wt + 3 * 65536, bo, ox, M);
  }
}